// Round 5
// baseline (140.132 us; speedup 1.0000x reference)
//
#include <hip/hip_runtime.h>
#include <math.h>

#define HH 2048
#define WW 4096

__device__ __forceinline__ float rcp_f(float x){ return __builtin_amdgcn_rcpf(x); }
__device__ __forceinline__ float rsq_f(float x){ return __builtin_amdgcn_rsqf(x); }

typedef float vf4 __attribute__((ext_vector_type(4)));

__device__ __forceinline__ void st_nt4(float* p, float a, float b, float c, float d){
    vf4 v = {a, b, c, d};
    __builtin_nontemporal_store(v, (vf4*)p);
}

__global__ __launch_bounds__(256)
void nim_kernel(const float* __restrict__ depth,
                const float* __restrict__ cam,
                const int*   __restrict__ signf,
                float* __restrict__ out)
{
    const int j0 = (blockIdx.x * 256 + threadIdx.x) * 8;   // 8 columns/thread
    const int i  = blockIdx.y;
    const size_t HW  = (size_t)HH * WW;
    const size_t idx = (size_t)i * WW + j0;

    const float cy = cam[5];

    // Rows i <= cy+1: C or U sign-masked => some D=+inf => all normalized
    // components NaN->0 => sums 0 => theta NaN => reference bad path (0,0,-1).
    if ((float)i <= cy + 1.0f){
        st_nt4(out + idx,              0.f, 0.f, 0.f, 0.f);
        st_nt4(out + idx + 4,          0.f, 0.f, 0.f, 0.f);
        st_nt4(out + HW + idx,         0.f, 0.f, 0.f, 0.f);
        st_nt4(out + HW + idx + 4,     0.f, 0.f, 0.f, 0.f);
        st_nt4(out + 2*HW + idx,      -1.f,-1.f,-1.f,-1.f);
        st_nt4(out + 2*HW + idx + 4,  -1.f,-1.f,-1.f,-1.f);
        return;
    }

    const float fx = cam[0], cx = cam[2], fy = cam[4];
    const float inv_fx = rcp_f(fx);
    const int   sf = signf[0];

    // Live region: rows i-1..i+1 all have (r-cy) >= 1 => Y > 0 (depth > 0),
    // so the reference's neg/NaN masks never fire here.
    const float rf_u = ((float)(i - 1) - cy) * inv_fx;
    const float rf_c = ((float)i       - cy) * inv_fx;
    const float rf_d = ((float)(i + 1) - cy) * inv_fx;

    const float* rowc = depth + (size_t)i * WW + j0;
    const float* rowu = depth + (size_t)(i - 1) * WW + j0;

    float dc[10], du[8], dd[8];
    {
        const float4 a = *(const float4*)rowc;
        const float4 b = *(const float4*)(rowc + 4);
        dc[1]=a.x; dc[2]=a.y; dc[3]=a.z; dc[4]=a.w;
        dc[5]=b.x; dc[6]=b.y; dc[7]=b.z; dc[8]=b.w;
        const float4 ua = *(const float4*)rowu;
        const float4 ub = *(const float4*)(rowu + 4);
        du[0]=ua.x; du[1]=ua.y; du[2]=ua.z; du[3]=ua.w;
        du[4]=ub.x; du[5]=ub.y; du[6]=ub.z; du[7]=ub.w;
    }
    const bool lv = (j0 > 0);
    const bool rv = (j0 + 8 < WW);
    dc[0] = lv ? rowc[-1] : 0.f;
    dc[9] = rv ? rowc[8]  : 0.f;

    const bool dv = (i + 1 < HH);
    if (dv){
        const float* rowd = depth + (size_t)(i + 1) * WW + j0;
        const float4 da = *(const float4*)rowd;
        const float4 db = *(const float4*)(rowd + 4);
        dd[0]=da.x; dd[1]=da.y; dd[2]=da.z; dd[3]=da.w;
        dd[4]=db.x; dd[5]=db.y; dd[6]=db.z; dd[7]=db.w;
    } else {
#pragma unroll
        for (int t = 0; t < 8; ++t) dd[t] = 0.f;
    }

    // D = 1/Z per position; zero-padded (OOB) positions have Z = D = 0.
    float Dc[10], Du[8], Dd[8];
#pragma unroll
    for (int t = 0; t < 10; ++t) Dc[t] = rcp_f(dc[t]);
    if (!lv) Dc[0] = 0.f;
    if (!rv) Dc[9] = 0.f;
#pragma unroll
    for (int t = 0; t < 8; ++t){
        Du[t] = rcp_f(du[t]);
        Dd[t] = dv ? rcp_f(dd[t]) : 0.f;
    }

    const float jb = ((float)(j0 - 1) - cx) * inv_fx;  // cf(t) = jb + t*inv_fx

    float ox[8], oy[8], oz[8];
#pragma unroll
    for (int p = 0; p < 8; ++p){
        const float cfl = jb + (float)p       * inv_fx;
        const float cfc = jb + (float)(p + 1) * inv_fx;
        const float cfr = jb + (float)(p + 2) * inv_fx;
        const float CZ  = dc[p + 1];

        const float nx = (Dc[p + 2] - Dc[p]) * fx;   // Gu * fx
        const float ny = (Dd[p] - Du[p]) * fy;       // Gv * fy
        const float r2 = nx * nx + ny * ny;
        const float rr = rsq_f(r2);
        const float rs = copysignf(rr, nx);
        const float a  = -nx * rs;   // cos(atan(ny/nx)+pi)
        const float b  = -ny * rs;   // sin(atan(ny/nx)+pi)

        // directions: up, left, right, down.  Using X=Z*cf, Y=Z*rf:
        //   same-col: Xd = cfc*w,           Yd = rf_c*CZ - rf_n*NZ
        //   same-row: Xd = cfc*CZ - cf_n*NZ, Yd = rf_c*w
        float hk[4], vzk[4];
        int npos = 0, nneg = 0;
#pragma unroll
        for (int k = 0; k < 4; ++k){
            float NZ, Xd, Yd;
            if (k == 0){ NZ = du[p];     const float w0 = CZ - NZ;
                         Xd = cfc * w0;  Yd = rf_c * CZ - rf_u * NZ; }
            else if (k == 1){ NZ = dc[p];     Xd = cfc * CZ - cfl * NZ;
                              Yd = rf_c * (CZ - NZ); }
            else if (k == 2){ NZ = dc[p + 2]; Xd = cfc * CZ - cfr * NZ;
                              Yd = rf_c * (CZ - NZ); }
            else            { NZ = dd[p];     const float w0 = CZ - NZ;
                              Xd = cfc * w0;  Yd = rf_c * CZ - rf_d * NZ; }
            const float w   = CZ - NZ;
            const float g   = nx * Xd + ny * Yd;      // nzi = -g/w
            const float arg = (r2 * w) * w + g * g;   // w^2*(r2 + nzi^2)
            const float rn  = rsq_f(arg);
            float h  = fabsf(w) * rn;                 // 1/norm
            float vz = -g * copysignf(rn, w);
            // ref corners: arg==0 -> all components NaN->0;
            //              w==0,g!=0 -> vz=inf/inf=NaN->0 (h already 0)
            const bool za = (arg == 0.f);
            if (za) h = 0.f;
            if (za || (w == 0.f)) vz = 0.f;
            hk[k] = h; vzk[k] = vz;
            npos += (vz > 0.f);
            nneg += (vz < 0.f);
        }

        const bool posm = (npos >= nneg);
        float H = 0.f, sz = 0.f;
#pragma unroll
        for (int k = 0; k < 4; ++k){
            const float vz = vzk[k];
            const bool keep = !sf || (posm ? (vz > 0.f) : (vz < 0.f));
            const float fm = keep ? 1.f : 0.f;
            H  += hk[k] * fm;
            sz += vz    * fm;
        }

        // sx*a + sy*b = -copysign(sqrt(r2),nx)*H  (since vx_k=nx*h_k, vy_k=ny*h_k)
        const float cs = copysignf(r2 * rr, nx);      // r2==0 -> NaN (ref bad path)
        const float q  = (-cs * H) * rcp_f(sz);       // 0*inf=NaN, f*inf=+-inf as ref
        const float q2 = q * q;
        const float ct = rsq_f(1.f + q2);
        float st = q * ct;                            // sin(atan q)
        if (isinf(q2)) st = copysignf(1.f, q);        // |q| huge -> +-1

        float onx = st * a, ony = st * b, onz = ct;   // ct NaN iff ref bad path
        if (isnan(onz)){ onx = 0.f; ony = 0.f; onz = -1.f; }
        const float sgn = (ony > 0.f) ? -1.f : 1.f;
        ox[p] = onx * sgn; oy[p] = ony * sgn; oz[p] = onz * sgn;
    }

    st_nt4(out + idx,            ox[0], ox[1], ox[2], ox[3]);
    st_nt4(out + idx + 4,        ox[4], ox[5], ox[6], ox[7]);
    st_nt4(out + HW + idx,       oy[0], oy[1], oy[2], oy[3]);
    st_nt4(out + HW + idx + 4,   oy[4], oy[5], oy[6], oy[7]);
    st_nt4(out + 2*HW + idx,     oz[0], oz[1], oz[2], oz[3]);
    st_nt4(out + 2*HW + idx + 4, oz[4], oz[5], oz[6], oz[7]);
}

extern "C" void kernel_launch(void* const* d_in, const int* in_sizes, int n_in,
                              void* d_out, int out_size, void* d_ws, size_t ws_size,
                              hipStream_t stream) {
    const float* depth = (const float*)d_in[0];
    const float* cam   = (const float*)d_in[1];
    const int*   signf = (const int*)d_in[2];
    float* out = (float*)d_out;

    dim3 block(256, 1, 1);
    dim3 grid(WW / (256 * 8), HH, 1);
    nim_kernel<<<grid, block, 0, stream>>>(depth, cam, signf, out);
}

// Round 6
// 132.890 us; speedup vs baseline: 1.0545x; 1.0545x over previous
//
#include <hip/hip_runtime.h>
#include <math.h>

#define HH 2048
#define WW 4096

__device__ __forceinline__ float rcp_f(float x){ return __builtin_amdgcn_rcpf(x); }
__device__ __forceinline__ float rsq_f(float x){ return __builtin_amdgcn_rsqf(x); }

typedef float vf4 __attribute__((ext_vector_type(4)));

__device__ __forceinline__ void st_nt4(float* p, float a, float b, float c, float d){
    vf4 v = {a, b, c, d};
    __builtin_nontemporal_store(v, (vf4*)p);
}

__global__ __launch_bounds__(256, 4)
void nim_kernel(const float* __restrict__ depth,
                const float* __restrict__ cam,
                const int*   __restrict__ signf,
                float* __restrict__ out)
{
    const int j0 = (blockIdx.x * 256 + threadIdx.x) * 4;   // 4 columns/thread
    const int i  = blockIdx.y;
    const size_t HW  = (size_t)HH * WW;
    const size_t idx = (size_t)i * WW + j0;

    const float cy = cam[5];

    // Rows i <= cy+1: C or U sign-masked => some D=+inf => all normalized
    // components NaN->0 => sums 0 => theta NaN => reference bad path (0,0,-1).
    if ((float)i <= cy + 1.0f){
        st_nt4(out + idx,         0.f, 0.f, 0.f, 0.f);
        st_nt4(out + HW + idx,    0.f, 0.f, 0.f, 0.f);
        st_nt4(out + 2*HW + idx, -1.f,-1.f,-1.f,-1.f);
        return;
    }

    const float fx = cam[0], cx = cam[2], fy = cam[4];
    const float inv_fx = rcp_f(fx);
    const int   sf = signf[0];

    // Live region: rows i-1..i+1 all have (r-cy) >= 1 => Y > 0 (depth > 0),
    // so the reference's neg/NaN masks never fire here.
    const float rf_u = ((float)(i - 1) - cy) * inv_fx;
    const float rf_c = ((float)i       - cy) * inv_fx;
    const float rf_d = ((float)(i + 1) - cy) * inv_fx;

    const float* rowc = depth + (size_t)i * WW + j0;
    const float* rowu = depth + (size_t)(i - 1) * WW + j0;

    float dc[6], du[4], dd[4];
    {
        const float4 a = *(const float4*)rowc;
        dc[1]=a.x; dc[2]=a.y; dc[3]=a.z; dc[4]=a.w;
        const float4 ua = *(const float4*)rowu;
        du[0]=ua.x; du[1]=ua.y; du[2]=ua.z; du[3]=ua.w;
    }
    const bool lv = (j0 > 0);
    const bool rv = (j0 + 4 < WW);
    dc[0] = lv ? rowc[-1] : 0.f;
    dc[5] = rv ? rowc[4]  : 0.f;

    const bool dv = (i + 1 < HH);
    if (dv){
        const float4 da = *(const float4*)(depth + (size_t)(i + 1) * WW + j0);
        dd[0]=da.x; dd[1]=da.y; dd[2]=da.z; dd[3]=da.w;
    } else {
#pragma unroll
        for (int t = 0; t < 4; ++t) dd[t] = 0.f;
    }

    // D = 1/Z per position; zero-padded (OOB) positions have Z = D = 0.
    float Dc[6], Du[4], Dd[4];
#pragma unroll
    for (int t = 0; t < 6; ++t) Dc[t] = rcp_f(dc[t]);
    if (!lv) Dc[0] = 0.f;
    if (!rv) Dc[5] = 0.f;
#pragma unroll
    for (int t = 0; t < 4; ++t){
        Du[t] = rcp_f(du[t]);
        Dd[t] = dv ? rcp_f(dd[t]) : 0.f;
    }

    const float jb = ((float)(j0 - 1) - cx) * inv_fx;  // cf(t) = jb + t*inv_fx

    float ox[4], oy[4], oz[4];
#pragma unroll
    for (int p = 0; p < 4; ++p){
        const float cfl = jb + (float)p       * inv_fx;
        const float cfc = jb + (float)(p + 1) * inv_fx;
        const float cfr = jb + (float)(p + 2) * inv_fx;
        const float CZ  = dc[p + 1];

        const float nx = (Dc[p + 2] - Dc[p]) * fx;   // Gu * fx
        const float ny = (Dd[p] - Du[p]) * fy;       // Gv * fy
        const float r2 = nx * nx + ny * ny;
        const float rr = rsq_f(r2);
        const float rs = copysignf(rr, nx);
        const float a  = -nx * rs;   // cos(atan(ny/nx)+pi)
        const float b  = -ny * rs;   // sin(atan(ny/nx)+pi)

        // directions: up, left, right, down.  With X=Z*cf, Y=Z*rf:
        //   same-col: Xd = cfc*w,            Yd = rf_c*CZ - rf_n*NZ
        //   same-row: Xd = cfc*CZ - cf_n*NZ, Yd = rf_c*w
        float hk[4], vzk[4];
        int npos = 0, nneg = 0;
#pragma unroll
        for (int k = 0; k < 4; ++k){
            float NZ, Xd, Yd;
            if (k == 0){ NZ = du[p];     const float w0 = CZ - NZ;
                         Xd = cfc * w0;  Yd = rf_c * CZ - rf_u * NZ; }
            else if (k == 1){ NZ = dc[p];     Xd = cfc * CZ - cfl * NZ;
                              Yd = rf_c * (CZ - NZ); }
            else if (k == 2){ NZ = dc[p + 2]; Xd = cfc * CZ - cfr * NZ;
                              Yd = rf_c * (CZ - NZ); }
            else            { NZ = dd[p];     const float w0 = CZ - NZ;
                              Xd = cfc * w0;  Yd = rf_c * CZ - rf_d * NZ; }
            const float w   = CZ - NZ;
            const float g   = nx * Xd + ny * Yd;      // nzi = -g/w
            const float arg = (r2 * w) * w + g * g;   // w^2*(r2 + nzi^2)
            const float rn  = rsq_f(arg);
            float h  = fabsf(w) * rn;                 // 1/norm
            float vz = -g * copysignf(rn, w);
            // ref corners: arg==0 -> all components NaN->0;
            //              w==0,g!=0 -> vz=inf/inf=NaN->0 (h already 0)
            const bool za = (arg == 0.f);
            if (za) h = 0.f;
            if (za || (w == 0.f)) vz = 0.f;
            hk[k] = h; vzk[k] = vz;
            npos += (vz > 0.f);
            nneg += (vz < 0.f);
        }

        const bool posm = (npos >= nneg);
        float H = 0.f, sz = 0.f;
#pragma unroll
        for (int k = 0; k < 4; ++k){
            const float vz = vzk[k];
            const bool keep = !sf || (posm ? (vz > 0.f) : (vz < 0.f));
            const float fm = keep ? 1.f : 0.f;
            H  += hk[k] * fm;
            sz += vz    * fm;
        }

        // sx*a + sy*b = -copysign(sqrt(r2),nx)*H  (since vx_k=nx*h_k, vy_k=ny*h_k)
        const float cs = copysignf(r2 * rr, nx);      // r2==0 -> NaN (ref bad path)
        const float q  = (-cs * H) * rcp_f(sz);       // 0*inf=NaN, f*inf=+-inf as ref
        const float q2 = q * q;
        const float ct = rsq_f(1.f + q2);
        float st = q * ct;                            // sin(atan q)
        if (isinf(q2)) st = copysignf(1.f, q);        // |q| huge -> +-1

        float onx = st * a, ony = st * b, onz = ct;   // ct NaN iff ref bad path
        if (isnan(onz)){ onx = 0.f; ony = 0.f; onz = -1.f; }
        const float sgn = (ony > 0.f) ? -1.f : 1.f;
        ox[p] = onx * sgn; oy[p] = ony * sgn; oz[p] = onz * sgn;
    }

    st_nt4(out + idx,        ox[0], ox[1], ox[2], ox[3]);
    st_nt4(out + HW + idx,   oy[0], oy[1], oy[2], oy[3]);
    st_nt4(out + 2*HW + idx, oz[0], oz[1], oz[2], oz[3]);
}

extern "C" void kernel_launch(void* const* d_in, const int* in_sizes, int n_in,
                              void* d_out, int out_size, void* d_ws, size_t ws_size,
                              hipStream_t stream) {
    const float* depth = (const float*)d_in[0];
    const float* cam   = (const float*)d_in[1];
    const int*   signf = (const int*)d_in[2];
    float* out = (float*)d_out;

    dim3 block(256, 1, 1);
    dim3 grid(WW / (256 * 4), HH, 1);
    nim_kernel<<<grid, block, 0, stream>>>(depth, cam, signf, out);
}